// Round 9
// baseline (1434.220 us; speedup 1.0000x reference)
//
#include <hip/hip_runtime.h>
#include <hip/hip_bf16.h>
#include <stdint.h>

#define NF 165
#define NH 128
#define KP 192          // padded K for MFMA
#define NCOLS 384
#define BSH 8           // rows per bucket = 256
#define BROWS 256
#define BCAP 6144       // bucket capacity (mean 4096, sigma 64 -> +32 sigma)

typedef __attribute__((ext_vector_type(8))) short bf16x8;
typedef __attribute__((ext_vector_type(4))) float f32x4;

// ---- bf16 helpers --------------------------------------------------------

__device__ __forceinline__ unsigned short f2bf(float f) {
    unsigned int u = __builtin_bit_cast(unsigned int, f);
    u = (u + 0x7FFFu + ((u >> 16) & 1u)) >> 16;   // RNE
    return (unsigned short)u;
}
__device__ __forceinline__ float bf2f_lo(unsigned int v) {
    return __builtin_bit_cast(float, v << 16);
}
__device__ __forceinline__ float bf2f_hi(unsigned int v) {
    return __builtin_bit_cast(float, v & 0xFFFF0000u);
}

// ---- CSR build ----------------------------------------------------------

__global__ __launch_bounds__(256) void k_count(
        const int* __restrict__ erow, int* __restrict__ cnt, int E) {
    int e = blockIdx.x * 256 + threadIdx.x;
    if (e >= E) return;
    atomicAdd(&cnt[erow[e]], 1);
}

__global__ __launch_bounds__(256) void k_dis(
        const int* __restrict__ cnt, float* __restrict__ dis, int N) {
    int i = blockIdx.x * 256 + threadIdx.x;
    if (i >= N) return;
    int d = cnt[i];
    dis[i] = (d > 0) ? rsqrtf((float)d) : 0.0f;
}

__global__ __launch_bounds__(256) void k_scan1(
        const int* __restrict__ cnt, int* __restrict__ off,
        int* __restrict__ bsum, int N) {
    __shared__ int sh[256];
    int t = threadIdx.x;
    int base = blockIdx.x * 1024 + t * 4;
    int v0 = (base + 0 < N) ? cnt[base + 0] : 0;
    int v1 = (base + 1 < N) ? cnt[base + 1] : 0;
    int v2 = (base + 2 < N) ? cnt[base + 2] : 0;
    int v3 = (base + 3 < N) ? cnt[base + 3] : 0;
    int tsum = v0 + v1 + v2 + v3;
    sh[t] = tsum;
    __syncthreads();
#pragma unroll
    for (int ofs = 1; ofs < 256; ofs <<= 1) {
        int x = (t >= ofs) ? sh[t - ofs] : 0;
        __syncthreads();
        sh[t] += x;
        __syncthreads();
    }
    int excl = sh[t] - tsum;
    if (t == 255) bsum[blockIdx.x] = sh[t];
    if (base + 0 < N) off[base + 0] = excl;
    excl += v0;
    if (base + 1 < N) off[base + 1] = excl;
    excl += v1;
    if (base + 2 < N) off[base + 2] = excl;
    excl += v2;
    if (base + 3 < N) off[base + 3] = excl;
}

__global__ __launch_bounds__(256) void k_scan2(int* __restrict__ bsum, int NB) {
    __shared__ int sh[256];
    int t = threadIdx.x;
    int v = (t < NB) ? bsum[t] : 0;
    sh[t] = v;
    __syncthreads();
#pragma unroll
    for (int ofs = 1; ofs < 256; ofs <<= 1) {
        int x = (t >= ofs) ? sh[t - ofs] : 0;
        __syncthreads();
        sh[t] += x;
        __syncthreads();
    }
    if (t < NB) bsum[t] = sh[t] - v;
}

__global__ __launch_bounds__(256) void k_scan3(
        int* __restrict__ off, const int* __restrict__ bsum, int N, int E) {
    int i = blockIdx.x * 256 + threadIdx.x;
    if (i >= N) return;
    off[i] = off[i] + bsum[i >> 10];
    if (i == 0) off[N] = E;
}

// Level-1: scatter edges into 256-row buckets. Stores hit ~782 hot stream
// heads (L2-resident) instead of 12.8 MB of cold lines.
__global__ __launch_bounds__(256) void k_bucket(
        const int* __restrict__ erow, const int* __restrict__ ecol,
        int* __restrict__ bcur, unsigned int* __restrict__ bkt, int E) {
    int e = blockIdx.x * 256 + threadIdx.x;
    if (e >= E) return;
    int r = erow[e];
    int c = ecol[e];
    int b = r >> BSH;
    int pos = atomicAdd(&bcur[b], 1);
    if (pos < BCAP)
        bkt[(size_t)b * BCAP + pos] = ((unsigned)(r & (BROWS - 1)) << 18) | (unsigned)c;
}

// Level-2: one block per bucket; place edges at exact CSR slots via LDS,
// then stream out coalesced. Bucket's scol region is contiguous.
__global__ __launch_bounds__(256) void k_emit(
        const int* __restrict__ bcur, const unsigned int* __restrict__ bkt,
        const int* __restrict__ off, int* __restrict__ scol, int N) {
    __shared__ unsigned colbuf[BCAP];
    __shared__ int rowoff[BROWS + 1];
    __shared__ int cursor[BROWS];

    int b = blockIdx.x;
    int base = b << BSH;
    int nrows = N - base;
    if (nrows > BROWS) nrows = BROWS;
    int t = threadIdx.x;

    for (int i = t; i <= nrows; i += 256) rowoff[i] = off[base + i];
    if (t < BROWS) cursor[t] = 0;
    __syncthreads();

    int regionStart = rowoff[0];
    int total = rowoff[nrows] - regionStart;
    int nb = bcur[b];
    if (nb > BCAP) nb = BCAP;

    for (int i = t; i < nb; i += 256) {
        unsigned v = bkt[(size_t)b * BCAP + i];
        int rl = v >> 18;
        unsigned c = v & 0x3FFFFu;
        int pos = (rowoff[rl] - regionStart) + atomicAdd(&cursor[rl], 1);
        if (pos < BCAP) colbuf[pos] = c;
    }
    __syncthreads();

    for (int i = t; i < total; i += 256) scol[regionStart + i] = (int)colbuf[i];
}

// ---- conversions ---------------------------------------------------------

__global__ __launch_bounds__(256) void k_xb(
        const float* __restrict__ x, unsigned short* __restrict__ xb, int N) {
    int gid = blockIdx.x * 256 + threadIdx.x;
    if (gid >= N * (KP / 8)) return;
    int row = gid / (KP / 8);
    int k0 = (gid % (KP / 8)) * 8;
    unsigned short v[8];
#pragma unroll
    for (int i = 0; i < 8; ++i) {
        int k = k0 + i;
        v[i] = (k < NF) ? f2bf(x[(size_t)row * NF + k]) : (unsigned short)0;
    }
    uint4 pk;
    pk.x = (unsigned)v[0] | ((unsigned)v[1] << 16);
    pk.y = (unsigned)v[2] | ((unsigned)v[3] << 16);
    pk.z = (unsigned)v[4] | ((unsigned)v[5] << 16);
    pk.w = (unsigned)v[6] | ((unsigned)v[7] << 16);
    *(uint4*)(xb + (size_t)row * KP + k0) = pk;
}

__global__ __launch_bounds__(256) void k_wbt(
        const float* __restrict__ W1, unsigned short* __restrict__ wbt) {
    int gid = blockIdx.x * 256 + threadIdx.x;
    if (gid >= NCOLS * (KP / 8)) return;
    int col = gid / (KP / 8);
    int k0 = (gid % (KP / 8)) * 8;
    int cc = col & 127;
    unsigned short v[8];
#pragma unroll
    for (int i = 0; i < 8; ++i) {
        int k = k0 + i;
        float f = 0.0f;
        if (k < NF) {
            if (col < 128)      f = W1[k * 128 + cc] - W1[42240 + k * 128 + cc];
            else if (col < 256) f = W1[21120 + k * 128 + cc];
            else                f = W1[42240 + k * 128 + cc];
        }
        v[i] = f2bf(f);
    }
    uint4 pk;
    pk.x = (unsigned)v[0] | ((unsigned)v[1] << 16);
    pk.y = (unsigned)v[2] | ((unsigned)v[3] << 16);
    pk.z = (unsigned)v[4] | ((unsigned)v[5] << 16);
    pk.w = (unsigned)v[6] | ((unsigned)v[7] << 16);
    *(uint4*)(wbt + (size_t)col * KP + k0) = pk;
}

// Wc2[128][8] with k in interleaved-hidden layout: k_lin 2c->(c), 2c+1->(c+64)
__global__ __launch_bounds__(256) void k_wc2(const float* __restrict__ W2,
                                             float* __restrict__ Wc2) {
    int gid = blockIdx.x * 256 + threadIdx.x;
    if (gid >= 128 * 8) return;
    int k = gid >> 3;
    int c = gid & 7;
    int ko = (k & 1) ? (k >> 1) + 64 : (k >> 1);
    float v = 0.0f;
    if (c < 2)      v = W2[ko * 2 + c] - W2[512 + ko * 2 + c];
    else if (c < 4) v = W2[256 + ko * 2 + (c - 2)];
    else if (c < 6) v = W2[512 + ko * 2 + (c - 4)];
    Wc2[gid] = v;
}

// ---- GEMM1 via MFMA ------------------------------------------------------
// g==0 -> ub = u (bf16); g==1 -> sA = dis*s (bf16); g==2 -> wb = dis*w (bf16)
__global__ __launch_bounds__(256) void k_gemm1_mfma(
        const unsigned short* __restrict__ xb, const unsigned short* __restrict__ wbt,
        const float* __restrict__ dis,
        unsigned int* __restrict__ ub, unsigned int* __restrict__ sA,
        unsigned int* __restrict__ wb, int N) {
    __shared__ unsigned short As[128][40];
    __shared__ unsigned short Bs[128][40];

    int tid = threadIdx.x;
    int w = tid >> 6;
    int lane = tid & 63;
    int l15 = lane & 15;
    int l16 = lane >> 4;
    int g = blockIdx.x;
    int brow = blockIdx.y * 128;
    int gcol = g * 128;

    int sr = tid >> 1;
    int sk = (tid & 1) * 16;

    f32x4 acc[2][8] = {};

    for (int kc = 0; kc < 6; ++kc) {
        int k0 = kc * 32;
        uint4 va0 = {0, 0, 0, 0}, va1 = {0, 0, 0, 0};
        if (brow + sr < N) {
            const unsigned short* asrc = xb + (size_t)(brow + sr) * KP + k0 + sk;
            va0 = *(const uint4*)asrc;
            va1 = *(const uint4*)(asrc + 8);
        }
        const unsigned short* bsrc = wbt + (size_t)(gcol + sr) * KP + k0 + sk;
        uint4 vb0 = *(const uint4*)bsrc;
        uint4 vb1 = *(const uint4*)(bsrc + 8);
        __syncthreads();
        *(uint4*)&As[sr][sk] = va0;
        *(uint4*)&As[sr][sk + 8] = va1;
        *(uint4*)&Bs[sr][sk] = vb0;
        *(uint4*)&Bs[sr][sk + 8] = vb1;
        __syncthreads();

        bf16x8 a[2], b[8];
#pragma unroll
        for (int m = 0; m < 2; ++m)
            a[m] = *(const bf16x8*)&As[w * 32 + m * 16 + l15][l16 * 8];
#pragma unroll
        for (int n = 0; n < 8; ++n)
            b[n] = *(const bf16x8*)&Bs[n * 16 + l15][l16 * 8];
#pragma unroll
        for (int m = 0; m < 2; ++m)
#pragma unroll
            for (int n = 0; n < 8; ++n)
                acc[m][n] = __builtin_amdgcn_mfma_f32_16x16x32_bf16(
                    a[m], b[n], acc[m][n], 0, 0, 0);
    }

    unsigned int* dst = (g == 0) ? ub : (g == 1) ? sA : wb;
#pragma unroll
    for (int m = 0; m < 2; ++m) {
#pragma unroll
        for (int reg = 0; reg < 4; ++reg) {
            int row = brow + w * 32 + m * 16 + l16 * 4 + reg;
            if (row >= N) continue;
            float sc = (g == 0) ? 1.0f : dis[row];
#pragma unroll
            for (int n = 0; n < 4; ++n) {
                int c = n * 16 + l15;
                float lo = sc * acc[m][n][reg];
                float hi = sc * acc[m][n + 4][reg];
                dst[(size_t)row * 64 + c] =
                    (unsigned)f2bf(lo) | ((unsigned)f2bf(hi) << 16);
            }
        }
    }
}

// ---- 128-wide props: 4 rows/wave, 16 lanes/row, uint4 gathers, unroll-2 ---

// sb[r] = bf16( sA[r] - 2*dis[r]^2 * sum_e wb[col] )
__global__ __launch_bounds__(256) void k_prop_b2b(
        const int* __restrict__ off, const int* __restrict__ scol,
        const unsigned int* __restrict__ srcb, const unsigned int* __restrict__ addb,
        const float* __restrict__ dis, unsigned int* __restrict__ dstb, int N) {
    int wid = (blockIdx.x * 256 + threadIdx.x) >> 6;
    int lane = threadIdx.x & 63;
    int g = lane >> 4, q = lane & 15;
    int r = wid * 4 + g;
    if (r >= N) return;
    int e = off[r], end = off[r + 1];
    const uint4* src4 = (const uint4*)srcb;
    float a[8] = {}, b[8] = {};
    for (; e + 2 <= end; e += 2) {
        int c0 = scol[e], c1 = scol[e + 1];
        uint4 v0 = src4[(size_t)c0 * 16 + q];
        uint4 v1 = src4[(size_t)c1 * 16 + q];
        unsigned vv0[4] = {v0.x, v0.y, v0.z, v0.w};
        unsigned vv1[4] = {v1.x, v1.y, v1.z, v1.w};
#pragma unroll
        for (int j = 0; j < 4; ++j) {
            a[2 * j] += bf2f_lo(vv0[j]); a[2 * j + 1] += bf2f_hi(vv0[j]);
            b[2 * j] += bf2f_lo(vv1[j]); b[2 * j + 1] += bf2f_hi(vv1[j]);
        }
    }
    if (e < end) {
        int c0 = scol[e];
        uint4 v0 = src4[(size_t)c0 * 16 + q];
        unsigned vv0[4] = {v0.x, v0.y, v0.z, v0.w};
#pragma unroll
        for (int j = 0; j < 4; ++j) {
            a[2 * j] += bf2f_lo(vv0[j]); a[2 * j + 1] += bf2f_hi(vv0[j]);
        }
    }
    float d = dis[r];
    float m2 = -2.0f * d * d;
    uint4 ad = ((const uint4*)addb)[(size_t)r * 16 + q];
    unsigned adp[4] = {ad.x, ad.y, ad.z, ad.w};
    uint4 o;
    unsigned* op = (unsigned*)&o;
#pragma unroll
    for (int j = 0; j < 4; ++j) {
        float lo = bf2f_lo(adp[j]) + m2 * (a[2 * j] + b[2 * j]);
        float hi = bf2f_hi(adp[j]) + m2 * (a[2 * j + 1] + b[2 * j + 1]);
        op[j] = (unsigned)f2bf(lo) | ((unsigned)f2bf(hi) << 16);
    }
    ((uint4*)dstb)[(size_t)r * 16 + q] = o;
}

// hb[r] = bf16( relu( ub[r] - dis[r] * sum_e sb[col] + b1 ) )
__global__ __launch_bounds__(256) void k_prop_b2f_relu(
        const int* __restrict__ off, const int* __restrict__ scol,
        const unsigned int* __restrict__ srcb, const unsigned int* __restrict__ addb,
        const float* __restrict__ dis, const float* __restrict__ b1,
        unsigned int* __restrict__ hb, int N) {
    int wid = (blockIdx.x * 256 + threadIdx.x) >> 6;
    int lane = threadIdx.x & 63;
    int g = lane >> 4, q = lane & 15;
    int r = wid * 4 + g;
    if (r >= N) return;
    int e = off[r], end = off[r + 1];
    const uint4* src4 = (const uint4*)srcb;
    float a[8] = {}, b[8] = {};
    for (; e + 2 <= end; e += 2) {
        int c0 = scol[e], c1 = scol[e + 1];
        uint4 v0 = src4[(size_t)c0 * 16 + q];
        uint4 v1 = src4[(size_t)c1 * 16 + q];
        unsigned vv0[4] = {v0.x, v0.y, v0.z, v0.w};
        unsigned vv1[4] = {v1.x, v1.y, v1.z, v1.w};
#pragma unroll
        for (int j = 0; j < 4; ++j) {
            a[2 * j] += bf2f_lo(vv0[j]); a[2 * j + 1] += bf2f_hi(vv0[j]);
            b[2 * j] += bf2f_lo(vv1[j]); b[2 * j + 1] += bf2f_hi(vv1[j]);
        }
    }
    if (e < end) {
        int c0 = scol[e];
        uint4 v0 = src4[(size_t)c0 * 16 + q];
        unsigned vv0[4] = {v0.x, v0.y, v0.z, v0.w};
#pragma unroll
        for (int j = 0; j < 4; ++j) {
            a[2 * j] += bf2f_lo(vv0[j]); a[2 * j + 1] += bf2f_hi(vv0[j]);
        }
    }
    float m1 = -dis[r];
    uint4 ad = ((const uint4*)addb)[(size_t)r * 16 + q];
    unsigned adp[4] = {ad.x, ad.y, ad.z, ad.w};
    uint4 o;
    unsigned* op = (unsigned*)&o;
#pragma unroll
    for (int j = 0; j < 4; ++j) {
        int c = q * 4 + j;
        float lo = fmaxf(bf2f_lo(adp[j]) + m1 * (a[2 * j] + b[2 * j]) + b1[c], 0.0f);
        float hi = fmaxf(bf2f_hi(adp[j]) + m1 * (a[2 * j + 1] + b[2 * j + 1]) + b1[c + 64], 0.0f);
        op[j] = (unsigned)f2bf(lo) | ((unsigned)f2bf(hi) << 16);
    }
    ((uint4*)hb)[(size_t)r * 16 + q] = o;
}

// GEMM2: hb[N,64] (bf16 pairs) @ Wc2[128,8] -> out(+b2) f32, s2=dis*s2raw, w2=dis*w2raw
__global__ __launch_bounds__(256) void k_gemm2(
        const unsigned int* __restrict__ hb, const float* __restrict__ Wc2,
        const float* __restrict__ b2, const float* __restrict__ dis,
        float* __restrict__ out, float* __restrict__ s2, float* __restrict__ w2,
        int N) {
    __shared__ float Ws[128 * 8];
    int tid = threadIdx.x;
    for (int idx = tid; idx < 128 * 8; idx += 256) Ws[idx] = Wc2[idx];
    __syncthreads();

    int rl = tid >> 3;
    int sub = tid & 7;
    int row = blockIdx.x * 32 + rl;
    if (row >= N) return;

    float4 accA = {0, 0, 0, 0};
    float4 accB = {0, 0, 0, 0};
    const uint4* hp = (const uint4*)(hb + (size_t)row * 64 + sub * 8);
#pragma unroll
    for (int qq = 0; qq < 2; ++qq) {
        uint4 hv = hp[qq];
        unsigned hu[4] = {hv.x, hv.y, hv.z, hv.w};
#pragma unroll
        for (int t = 0; t < 4; ++t) {
            int kl = sub * 16 + qq * 8 + 2 * t;
            float he0 = bf2f_lo(hu[t]);
            float he1 = bf2f_hi(hu[t]);
            const float* w0 = &Ws[kl * 8];
            const float* w1 = &Ws[(kl + 1) * 8];
            accA.x += he0 * w0[0] + he1 * w1[0];
            accA.y += he0 * w0[1] + he1 * w1[1];
            accA.z += he0 * w0[2] + he1 * w1[2];
            accA.w += he0 * w0[3] + he1 * w1[3];
            accB.x += he0 * w0[4] + he1 * w1[4];
            accB.y += he0 * w0[5] + he1 * w1[5];
        }
    }
#pragma unroll
    for (int off = 4; off; off >>= 1) {
        accA.x += __shfl_xor(accA.x, off);
        accA.y += __shfl_xor(accA.y, off);
        accA.z += __shfl_xor(accA.z, off);
        accA.w += __shfl_xor(accA.w, off);
        accB.x += __shfl_xor(accB.x, off);
        accB.y += __shfl_xor(accB.y, off);
    }
    if (sub == 0) {
        float d = dis[row];
        out[(size_t)row * 2 + 0] = accA.x + b2[0];
        out[(size_t)row * 2 + 1] = accA.y + b2[1];
        s2[(size_t)row * 2 + 0] = d * accA.z;
        s2[(size_t)row * 2 + 1] = d * accA.w;
        w2[(size_t)row * 2 + 0] = d * accB.x;
        w2[(size_t)row * 2 + 1] = d * accB.y;
    }
}

// CSR prop, 2-wide: dst[r] = add[r] + m * sum src[col], m = sq ? -2*dis^2 : -dis.
__global__ __launch_bounds__(256) void k_prop2_csr(
        const int* __restrict__ off, const int* __restrict__ scol,
        const float* __restrict__ src, const float* __restrict__ add,
        const float* __restrict__ dis, float* __restrict__ dst,
        int sq, int N) {
    int r = blockIdx.x * 256 + threadIdx.x;
    if (r >= N) return;
    int e0 = off[r], e1 = off[r + 1];
    float a0 = 0.0f, a1 = 0.0f;
    for (int e = e0; e < e1; ++e) {
        int c = scol[e];
        float2 v = *(const float2*)(src + (size_t)c * 2);
        a0 += v.x;
        a1 += v.y;
    }
    float d = dis[r];
    float m = sq ? (-2.0f * d * d) : (-d);
    float2 ad = *(const float2*)(add + (size_t)r * 2);
    float2 o = {ad.x + m * a0, ad.y + m * a1};
    *(float2*)(dst + (size_t)r * 2) = o;
}

extern "C" void kernel_launch(void* const* d_in, const int* in_sizes, int n_in,
                              void* d_out, int out_size, void* d_ws, size_t ws_size,
                              hipStream_t stream) {
    const float* x   = (const float*)d_in[0];
    const int* eidx  = (const int*)d_in[1];
    const float* W1  = (const float*)d_in[2];
    const float* b1  = (const float*)d_in[3];
    const float* W2  = (const float*)d_in[4];
    const float* b2  = (const float*)d_in[5];
    float* out       = (float*)d_out;

    int N = in_sizes[0] / NF;
    int E = in_sizes[1] / 2;
    const int* erow = eidx;
    const int* ecol = eidx + E;
    int NBK = (N + BROWS - 1) >> BSH;

    char* p = (char*)d_ws;
    auto alloc = [&](size_t bytes) {
        char* q = p;
        p += (bytes + 255) & ~(size_t)255;
        return q;
    };
    unsigned int* ub = (unsigned int*)alloc((size_t)N * 64 * 4);
    unsigned int* sA = (unsigned int*)alloc((size_t)N * 64 * 4);
    unsigned int* wb = (unsigned int*)alloc((size_t)N * 64 * 4);  // reused as hb
    unsigned int* sb = (unsigned int*)alloc((size_t)N * 64 * 4);
    unsigned short* xb  = (unsigned short*)alloc((size_t)N * KP * 2);
    unsigned short* wbt = (unsigned short*)alloc((size_t)NCOLS * KP * 2);
    float* dis  = (float*)alloc((size_t)N * 4);
    int* cnt    = (int*)alloc((size_t)N * 4);
    int* off    = (int*)alloc((size_t)(N + 1) * 4);
    int* bsum   = (int*)alloc((size_t)256 * 4);
    int* bcur   = (int*)alloc((size_t)NBK * 4);
    unsigned int* bkt = (unsigned int*)alloc((size_t)NBK * BCAP * 4);
    int* scol   = (int*)alloc((size_t)E * 4);
    float* Wc2  = (float*)alloc((size_t)128 * 8 * 4);
    float* s2   = (float*)alloc((size_t)N * 2 * 4);
    float* w2   = (float*)alloc((size_t)N * 2 * 4);

    hipMemsetAsync(cnt, 0, (size_t)N * 4, stream);
    hipMemsetAsync(bcur, 0, (size_t)NBK * 4, stream);

    int gE = (E + 255) / 256;
    int gN = (N + 255) / 256;
    int NB = (N + 1023) / 1024;

    // conversions
    k_xb<<<(N * (KP / 8) + 255) / 256, 256, 0, stream>>>(x, xb, N);
    k_wbt<<<(NCOLS * (KP / 8) + 255) / 256, 256, 0, stream>>>(W1, wbt);
    k_wc2<<<4, 256, 0, stream>>>(W2, Wc2);

    // CSR build (bucketed)
    k_count<<<gE, 256, 0, stream>>>(erow, cnt, E);
    k_dis<<<gN, 256, 0, stream>>>(cnt, dis, N);
    k_scan1<<<NB, 256, 0, stream>>>(cnt, off, bsum, N);
    k_scan2<<<1, 256, 0, stream>>>(bsum, NB);
    k_scan3<<<gN, 256, 0, stream>>>(off, bsum, N, E);
    k_bucket<<<gE, 256, 0, stream>>>(erow, ecol, bcur, bkt, E);
    k_emit<<<NBK, 256, 0, stream>>>(bcur, bkt, off, scol, N);

    // layer 1: MFMA GEMM (g fast-varying for xb L2 reuse)
    dim3 g1(3, (N + 127) / 128);
    k_gemm1_mfma<<<g1, 256, 0, stream>>>(xb, wbt, dis, ub, sA, wb, N);

    int nw4 = (N + 3) / 4;
    int gP4 = (nw4 * 64 + 255) / 256;
    // sb = bf16( sA - 2*dis^2 * prop-sum(wb) )
    k_prop_b2b<<<gP4, 256, 0, stream>>>(off, scol, wb, sA, dis, sb, N);
    // hb(=wb) = bf16 relu( ub - dis * prop-sum(sb) + b1 )
    k_prop_b2f_relu<<<gP4, 256, 0, stream>>>(off, scol, sb, ub, dis, b1, wb, N);

    // layer 2
    k_gemm2<<<(N + 31) / 32, 256, 0, stream>>>(wb, Wc2, b2, dis, out, s2, w2, N);
    k_prop2_csr<<<gN, 256, 0, stream>>>(off, scol, w2, s2, dis, s2, 1, N);
    k_prop2_csr<<<gN, 256, 0, stream>>>(off, scol, s2, out, dis, out, 0, N);
}

// Round 10
// 933.464 us; speedup vs baseline: 1.5364x; 1.5364x over previous
//
#include <hip/hip_runtime.h>
#include <hip/hip_bf16.h>
#include <stdint.h>

#define NF 165
#define NH 128
#define KP 192          // padded K for MFMA
#define NCOLS 384
#define BSH 8           // rows per bucket = 256
#define BROWS 256
#define BCAP 6144       // bucket capacity (mean 4096, sigma 64 -> +32 sigma)
#define CPAD 16         // cursor padding: 16 ints = 64B, one cache line per cursor

typedef __attribute__((ext_vector_type(8))) short bf16x8;
typedef __attribute__((ext_vector_type(4))) float f32x4;

// ---- bf16 helpers --------------------------------------------------------

__device__ __forceinline__ unsigned short f2bf(float f) {
    unsigned int u = __builtin_bit_cast(unsigned int, f);
    u = (u + 0x7FFFu + ((u >> 16) & 1u)) >> 16;   // RNE
    return (unsigned short)u;
}
__device__ __forceinline__ float bf2f_lo(unsigned int v) {
    return __builtin_bit_cast(float, v << 16);
}
__device__ __forceinline__ float bf2f_hi(unsigned int v) {
    return __builtin_bit_cast(float, v & 0xFFFF0000u);
}

// ---- CSR build ----------------------------------------------------------

__global__ __launch_bounds__(256) void k_count(
        const int* __restrict__ erow, int* __restrict__ cnt, int E) {
    int e = blockIdx.x * 256 + threadIdx.x;
    if (e >= E) return;
    atomicAdd(&cnt[erow[e]], 1);
}

__global__ __launch_bounds__(256) void k_dis(
        const int* __restrict__ cnt, float* __restrict__ dis, int N) {
    int i = blockIdx.x * 256 + threadIdx.x;
    if (i >= N) return;
    int d = cnt[i];
    dis[i] = (d > 0) ? rsqrtf((float)d) : 0.0f;
}

__global__ __launch_bounds__(256) void k_scan1(
        const int* __restrict__ cnt, int* __restrict__ off,
        int* __restrict__ bsum, int N) {
    __shared__ int sh[256];
    int t = threadIdx.x;
    int base = blockIdx.x * 1024 + t * 4;
    int v0 = (base + 0 < N) ? cnt[base + 0] : 0;
    int v1 = (base + 1 < N) ? cnt[base + 1] : 0;
    int v2 = (base + 2 < N) ? cnt[base + 2] : 0;
    int v3 = (base + 3 < N) ? cnt[base + 3] : 0;
    int tsum = v0 + v1 + v2 + v3;
    sh[t] = tsum;
    __syncthreads();
#pragma unroll
    for (int ofs = 1; ofs < 256; ofs <<= 1) {
        int x = (t >= ofs) ? sh[t - ofs] : 0;
        __syncthreads();
        sh[t] += x;
        __syncthreads();
    }
    int excl = sh[t] - tsum;
    if (t == 255) bsum[blockIdx.x] = sh[t];
    if (base + 0 < N) off[base + 0] = excl;
    excl += v0;
    if (base + 1 < N) off[base + 1] = excl;
    excl += v1;
    if (base + 2 < N) off[base + 2] = excl;
    excl += v2;
    if (base + 3 < N) off[base + 3] = excl;
}

__global__ __launch_bounds__(256) void k_scan2(int* __restrict__ bsum, int NB) {
    __shared__ int sh[256];
    int t = threadIdx.x;
    int v = (t < NB) ? bsum[t] : 0;
    sh[t] = v;
    __syncthreads();
#pragma unroll
    for (int ofs = 1; ofs < 256; ofs <<= 1) {
        int x = (t >= ofs) ? sh[t - ofs] : 0;
        __syncthreads();
        sh[t] += x;
        __syncthreads();
    }
    if (t < NB) bsum[t] = sh[t] - v;
}

__global__ __launch_bounds__(256) void k_scan3(
        int* __restrict__ off, const int* __restrict__ bsum, int N, int E) {
    int i = blockIdx.x * 256 + threadIdx.x;
    if (i >= N) return;
    off[i] = off[i] + bsum[i >> 10];
    if (i == 0) off[N] = E;
}

// Level-1: scatter edges into 256-row buckets. Cursors padded to one cache
// line each (CPAD) -- avoids 16-counters-per-line atomic ping-pong (r9 bug).
__global__ __launch_bounds__(256) void k_bucket(
        const int* __restrict__ erow, const int* __restrict__ ecol,
        int* __restrict__ bcur, unsigned int* __restrict__ bkt, int E) {
    int e = blockIdx.x * 256 + threadIdx.x;
    if (e >= E) return;
    int r = erow[e];
    int c = ecol[e];
    int b = r >> BSH;
    int pos = atomicAdd(&bcur[b * CPAD], 1);
    if (pos < BCAP)
        bkt[(size_t)b * BCAP + pos] = ((unsigned)(r & (BROWS - 1)) << 18) | (unsigned)c;
}

// Level-2: one block per bucket; place edges at exact CSR slots via LDS,
// then stream out coalesced.
__global__ __launch_bounds__(256) void k_emit(
        const int* __restrict__ bcur, const unsigned int* __restrict__ bkt,
        const int* __restrict__ off, int* __restrict__ scol, int N) {
    __shared__ unsigned colbuf[BCAP];
    __shared__ int rowoff[BROWS + 1];
    __shared__ int cursor[BROWS];

    int b = blockIdx.x;
    int base = b << BSH;
    int nrows = N - base;
    if (nrows > BROWS) nrows = BROWS;
    int t = threadIdx.x;

    for (int i = t; i <= nrows; i += 256) rowoff[i] = off[base + i];
    if (t < BROWS) cursor[t] = 0;
    __syncthreads();

    int regionStart = rowoff[0];
    int total = rowoff[nrows] - regionStart;
    int nb = bcur[b * CPAD];
    if (nb > BCAP) nb = BCAP;

    for (int i = t; i < nb; i += 256) {
        unsigned v = bkt[(size_t)b * BCAP + i];
        int rl = v >> 18;
        unsigned c = v & 0x3FFFFu;
        int pos = (rowoff[rl] - regionStart) + atomicAdd(&cursor[rl], 1);
        if (pos < BCAP) colbuf[pos] = c;
    }
    __syncthreads();

    for (int i = t; i < total; i += 256) scol[regionStart + i] = (int)colbuf[i];
}

// ---- conversions ---------------------------------------------------------

__global__ __launch_bounds__(256) void k_xb(
        const float* __restrict__ x, unsigned short* __restrict__ xb, int N) {
    int gid = blockIdx.x * 256 + threadIdx.x;
    if (gid >= N * (KP / 8)) return;
    int row = gid / (KP / 8);
    int k0 = (gid % (KP / 8)) * 8;
    unsigned short v[8];
#pragma unroll
    for (int i = 0; i < 8; ++i) {
        int k = k0 + i;
        v[i] = (k < NF) ? f2bf(x[(size_t)row * NF + k]) : (unsigned short)0;
    }
    uint4 pk;
    pk.x = (unsigned)v[0] | ((unsigned)v[1] << 16);
    pk.y = (unsigned)v[2] | ((unsigned)v[3] << 16);
    pk.z = (unsigned)v[4] | ((unsigned)v[5] << 16);
    pk.w = (unsigned)v[6] | ((unsigned)v[7] << 16);
    *(uint4*)(xb + (size_t)row * KP + k0) = pk;
}

__global__ __launch_bounds__(256) void k_wbt(
        const float* __restrict__ W1, unsigned short* __restrict__ wbt) {
    int gid = blockIdx.x * 256 + threadIdx.x;
    if (gid >= NCOLS * (KP / 8)) return;
    int col = gid / (KP / 8);
    int k0 = (gid % (KP / 8)) * 8;
    int cc = col & 127;
    unsigned short v[8];
#pragma unroll
    for (int i = 0; i < 8; ++i) {
        int k = k0 + i;
        float f = 0.0f;
        if (k < NF) {
            if (col < 128)      f = W1[k * 128 + cc] - W1[42240 + k * 128 + cc];
            else if (col < 256) f = W1[21120 + k * 128 + cc];
            else                f = W1[42240 + k * 128 + cc];
        }
        v[i] = f2bf(f);
    }
    uint4 pk;
    pk.x = (unsigned)v[0] | ((unsigned)v[1] << 16);
    pk.y = (unsigned)v[2] | ((unsigned)v[3] << 16);
    pk.z = (unsigned)v[4] | ((unsigned)v[5] << 16);
    pk.w = (unsigned)v[6] | ((unsigned)v[7] << 16);
    *(uint4*)(wbt + (size_t)col * KP + k0) = pk;
}

// Wc2[128][8] with k in interleaved-hidden layout: k_lin 2c->(c), 2c+1->(c+64)
__global__ __launch_bounds__(256) void k_wc2(const float* __restrict__ W2,
                                             float* __restrict__ Wc2) {
    int gid = blockIdx.x * 256 + threadIdx.x;
    if (gid >= 128 * 8) return;
    int k = gid >> 3;
    int c = gid & 7;
    int ko = (k & 1) ? (k >> 1) + 64 : (k >> 1);
    float v = 0.0f;
    if (c < 2)      v = W2[ko * 2 + c] - W2[512 + ko * 2 + c];
    else if (c < 4) v = W2[256 + ko * 2 + (c - 2)];
    else if (c < 6) v = W2[512 + ko * 2 + (c - 4)];
    Wc2[gid] = v;
}

// ---- GEMM1 via MFMA ------------------------------------------------------
// g==0 -> ub = u (bf16); g==1 -> sA = dis*s (bf16); g==2 -> wb = dis*w (bf16)
__global__ __launch_bounds__(256) void k_gemm1_mfma(
        const unsigned short* __restrict__ xb, const unsigned short* __restrict__ wbt,
        const float* __restrict__ dis,
        unsigned int* __restrict__ ub, unsigned int* __restrict__ sA,
        unsigned int* __restrict__ wb, int N) {
    __shared__ unsigned short As[128][40];
    __shared__ unsigned short Bs[128][40];

    int tid = threadIdx.x;
    int w = tid >> 6;
    int lane = tid & 63;
    int l15 = lane & 15;
    int l16 = lane >> 4;
    int g = blockIdx.x;
    int brow = blockIdx.y * 128;
    int gcol = g * 128;

    int sr = tid >> 1;
    int sk = (tid & 1) * 16;

    f32x4 acc[2][8] = {};

    for (int kc = 0; kc < 6; ++kc) {
        int k0 = kc * 32;
        uint4 va0 = {0, 0, 0, 0}, va1 = {0, 0, 0, 0};
        if (brow + sr < N) {
            const unsigned short* asrc = xb + (size_t)(brow + sr) * KP + k0 + sk;
            va0 = *(const uint4*)asrc;
            va1 = *(const uint4*)(asrc + 8);
        }
        const unsigned short* bsrc = wbt + (size_t)(gcol + sr) * KP + k0 + sk;
        uint4 vb0 = *(const uint4*)bsrc;
        uint4 vb1 = *(const uint4*)(bsrc + 8);
        __syncthreads();
        *(uint4*)&As[sr][sk] = va0;
        *(uint4*)&As[sr][sk + 8] = va1;
        *(uint4*)&Bs[sr][sk] = vb0;
        *(uint4*)&Bs[sr][sk + 8] = vb1;
        __syncthreads();

        bf16x8 a[2], b[8];
#pragma unroll
        for (int m = 0; m < 2; ++m)
            a[m] = *(const bf16x8*)&As[w * 32 + m * 16 + l15][l16 * 8];
#pragma unroll
        for (int n = 0; n < 8; ++n)
            b[n] = *(const bf16x8*)&Bs[n * 16 + l15][l16 * 8];
#pragma unroll
        for (int m = 0; m < 2; ++m)
#pragma unroll
            for (int n = 0; n < 8; ++n)
                acc[m][n] = __builtin_amdgcn_mfma_f32_16x16x32_bf16(
                    a[m], b[n], acc[m][n], 0, 0, 0);
    }

    unsigned int* dst = (g == 0) ? ub : (g == 1) ? sA : wb;
#pragma unroll
    for (int m = 0; m < 2; ++m) {
#pragma unroll
        for (int reg = 0; reg < 4; ++reg) {
            int row = brow + w * 32 + m * 16 + l16 * 4 + reg;
            if (row >= N) continue;
            float sc = (g == 0) ? 1.0f : dis[row];
#pragma unroll
            for (int n = 0; n < 4; ++n) {
                int c = n * 16 + l15;
                float lo = sc * acc[m][n][reg];
                float hi = sc * acc[m][n + 4][reg];
                dst[(size_t)row * 64 + c] =
                    (unsigned)f2bf(lo) | ((unsigned)f2bf(hi) << 16);
            }
        }
    }
}

// ---- 128-wide props: 4 rows/wave, 16 lanes/row, uint4 gathers, unroll-2 ---

// sb[r] = bf16( sA[r] - 2*dis[r]^2 * sum_e wb[col] )
__global__ __launch_bounds__(256) void k_prop_b2b(
        const int* __restrict__ off, const int* __restrict__ scol,
        const unsigned int* __restrict__ srcb, const unsigned int* __restrict__ addb,
        const float* __restrict__ dis, unsigned int* __restrict__ dstb, int N) {
    int wid = (blockIdx.x * 256 + threadIdx.x) >> 6;
    int lane = threadIdx.x & 63;
    int g = lane >> 4, q = lane & 15;
    int r = wid * 4 + g;
    if (r >= N) return;
    int e = off[r], end = off[r + 1];
    const uint4* src4 = (const uint4*)srcb;
    float a[8] = {}, b[8] = {};
    for (; e + 2 <= end; e += 2) {
        int c0 = scol[e], c1 = scol[e + 1];
        uint4 v0 = src4[(size_t)c0 * 16 + q];
        uint4 v1 = src4[(size_t)c1 * 16 + q];
        unsigned vv0[4] = {v0.x, v0.y, v0.z, v0.w};
        unsigned vv1[4] = {v1.x, v1.y, v1.z, v1.w};
#pragma unroll
        for (int j = 0; j < 4; ++j) {
            a[2 * j] += bf2f_lo(vv0[j]); a[2 * j + 1] += bf2f_hi(vv0[j]);
            b[2 * j] += bf2f_lo(vv1[j]); b[2 * j + 1] += bf2f_hi(vv1[j]);
        }
    }
    if (e < end) {
        int c0 = scol[e];
        uint4 v0 = src4[(size_t)c0 * 16 + q];
        unsigned vv0[4] = {v0.x, v0.y, v0.z, v0.w};
#pragma unroll
        for (int j = 0; j < 4; ++j) {
            a[2 * j] += bf2f_lo(vv0[j]); a[2 * j + 1] += bf2f_hi(vv0[j]);
        }
    }
    float d = dis[r];
    float m2 = -2.0f * d * d;
    uint4 ad = ((const uint4*)addb)[(size_t)r * 16 + q];
    unsigned adp[4] = {ad.x, ad.y, ad.z, ad.w};
    uint4 o;
    unsigned* op = (unsigned*)&o;
#pragma unroll
    for (int j = 0; j < 4; ++j) {
        float lo = bf2f_lo(adp[j]) + m2 * (a[2 * j] + b[2 * j]);
        float hi = bf2f_hi(adp[j]) + m2 * (a[2 * j + 1] + b[2 * j + 1]);
        op[j] = (unsigned)f2bf(lo) | ((unsigned)f2bf(hi) << 16);
    }
    ((uint4*)dstb)[(size_t)r * 16 + q] = o;
}

// hb[r] = bf16( relu( ub[r] - dis[r] * sum_e sb[col] + b1 ) )
__global__ __launch_bounds__(256) void k_prop_b2f_relu(
        const int* __restrict__ off, const int* __restrict__ scol,
        const unsigned int* __restrict__ srcb, const unsigned int* __restrict__ addb,
        const float* __restrict__ dis, const float* __restrict__ b1,
        unsigned int* __restrict__ hb, int N) {
    int wid = (blockIdx.x * 256 + threadIdx.x) >> 6;
    int lane = threadIdx.x & 63;
    int g = lane >> 4, q = lane & 15;
    int r = wid * 4 + g;
    if (r >= N) return;
    int e = off[r], end = off[r + 1];
    const uint4* src4 = (const uint4*)srcb;
    float a[8] = {}, b[8] = {};
    for (; e + 2 <= end; e += 2) {
        int c0 = scol[e], c1 = scol[e + 1];
        uint4 v0 = src4[(size_t)c0 * 16 + q];
        uint4 v1 = src4[(size_t)c1 * 16 + q];
        unsigned vv0[4] = {v0.x, v0.y, v0.z, v0.w};
        unsigned vv1[4] = {v1.x, v1.y, v1.z, v1.w};
#pragma unroll
        for (int j = 0; j < 4; ++j) {
            a[2 * j] += bf2f_lo(vv0[j]); a[2 * j + 1] += bf2f_hi(vv0[j]);
            b[2 * j] += bf2f_lo(vv1[j]); b[2 * j + 1] += bf2f_hi(vv1[j]);
        }
    }
    if (e < end) {
        int c0 = scol[e];
        uint4 v0 = src4[(size_t)c0 * 16 + q];
        unsigned vv0[4] = {v0.x, v0.y, v0.z, v0.w};
#pragma unroll
        for (int j = 0; j < 4; ++j) {
            a[2 * j] += bf2f_lo(vv0[j]); a[2 * j + 1] += bf2f_hi(vv0[j]);
        }
    }
    float m1 = -dis[r];
    uint4 ad = ((const uint4*)addb)[(size_t)r * 16 + q];
    unsigned adp[4] = {ad.x, ad.y, ad.z, ad.w};
    uint4 o;
    unsigned* op = (unsigned*)&o;
#pragma unroll
    for (int j = 0; j < 4; ++j) {
        int c = q * 4 + j;
        float lo = fmaxf(bf2f_lo(adp[j]) + m1 * (a[2 * j] + b[2 * j]) + b1[c], 0.0f);
        float hi = fmaxf(bf2f_hi(adp[j]) + m1 * (a[2 * j + 1] + b[2 * j + 1]) + b1[c + 64], 0.0f);
        op[j] = (unsigned)f2bf(lo) | ((unsigned)f2bf(hi) << 16);
    }
    ((uint4*)hb)[(size_t)r * 16 + q] = o;
}

// GEMM2: hb[N,64] (bf16 pairs) @ Wc2[128,8] -> out(+b2) f32, s2=dis*s2raw, w2=dis*w2raw
__global__ __launch_bounds__(256) void k_gemm2(
        const unsigned int* __restrict__ hb, const float* __restrict__ Wc2,
        const float* __restrict__ b2, const float* __restrict__ dis,
        float* __restrict__ out, float* __restrict__ s2, float* __restrict__ w2,
        int N) {
    __shared__ float Ws[128 * 8];
    int tid = threadIdx.x;
    for (int idx = tid; idx < 128 * 8; idx += 256) Ws[idx] = Wc2[idx];
    __syncthreads();

    int rl = tid >> 3;
    int sub = tid & 7;
    int row = blockIdx.x * 32 + rl;
    if (row >= N) return;

    float4 accA = {0, 0, 0, 0};
    float4 accB = {0, 0, 0, 0};
    const uint4* hp = (const uint4*)(hb + (size_t)row * 64 + sub * 8);
#pragma unroll
    for (int qq = 0; qq < 2; ++qq) {
        uint4 hv = hp[qq];
        unsigned hu[4] = {hv.x, hv.y, hv.z, hv.w};
#pragma unroll
        for (int t = 0; t < 4; ++t) {
            int kl = sub * 16 + qq * 8 + 2 * t;
            float he0 = bf2f_lo(hu[t]);
            float he1 = bf2f_hi(hu[t]);
            const float* w0 = &Ws[kl * 8];
            const float* w1 = &Ws[(kl + 1) * 8];
            accA.x += he0 * w0[0] + he1 * w1[0];
            accA.y += he0 * w0[1] + he1 * w1[1];
            accA.z += he0 * w0[2] + he1 * w1[2];
            accA.w += he0 * w0[3] + he1 * w1[3];
            accB.x += he0 * w0[4] + he1 * w1[4];
            accB.y += he0 * w0[5] + he1 * w1[5];
        }
    }
#pragma unroll
    for (int off = 4; off; off >>= 1) {
        accA.x += __shfl_xor(accA.x, off);
        accA.y += __shfl_xor(accA.y, off);
        accA.z += __shfl_xor(accA.z, off);
        accA.w += __shfl_xor(accA.w, off);
        accB.x += __shfl_xor(accB.x, off);
        accB.y += __shfl_xor(accB.y, off);
    }
    if (sub == 0) {
        float d = dis[row];
        out[(size_t)row * 2 + 0] = accA.x + b2[0];
        out[(size_t)row * 2 + 1] = accA.y + b2[1];
        s2[(size_t)row * 2 + 0] = d * accA.z;
        s2[(size_t)row * 2 + 1] = d * accA.w;
        w2[(size_t)row * 2 + 0] = d * accB.x;
        w2[(size_t)row * 2 + 1] = d * accB.y;
    }
}

// CSR prop, 2-wide: dst[r] = add[r] + m * sum src[col], m = sq ? -2*dis^2 : -dis.
__global__ __launch_bounds__(256) void k_prop2_csr(
        const int* __restrict__ off, const int* __restrict__ scol,
        const float* __restrict__ src, const float* __restrict__ add,
        const float* __restrict__ dis, float* __restrict__ dst,
        int sq, int N) {
    int r = blockIdx.x * 256 + threadIdx.x;
    if (r >= N) return;
    int e0 = off[r], e1 = off[r + 1];
    float a0 = 0.0f, a1 = 0.0f;
    for (int e = e0; e < e1; ++e) {
        int c = scol[e];
        float2 v = *(const float2*)(src + (size_t)c * 2);
        a0 += v.x;
        a1 += v.y;
    }
    float d = dis[r];
    float m = sq ? (-2.0f * d * d) : (-d);
    float2 ad = *(const float2*)(add + (size_t)r * 2);
    float2 o = {ad.x + m * a0, ad.y + m * a1};
    *(float2*)(dst + (size_t)r * 2) = o;
}

extern "C" void kernel_launch(void* const* d_in, const int* in_sizes, int n_in,
                              void* d_out, int out_size, void* d_ws, size_t ws_size,
                              hipStream_t stream) {
    const float* x   = (const float*)d_in[0];
    const int* eidx  = (const int*)d_in[1];
    const float* W1  = (const float*)d_in[2];
    const float* b1  = (const float*)d_in[3];
    const float* W2  = (const float*)d_in[4];
    const float* b2  = (const float*)d_in[5];
    float* out       = (float*)d_out;

    int N = in_sizes[0] / NF;
    int E = in_sizes[1] / 2;
    const int* erow = eidx;
    const int* ecol = eidx + E;
    int NBK = (N + BROWS - 1) >> BSH;

    char* p = (char*)d_ws;
    auto alloc = [&](size_t bytes) {
        char* q = p;
        p += (bytes + 255) & ~(size_t)255;
        return q;
    };
    unsigned int* ub = (unsigned int*)alloc((size_t)N * 64 * 4);
    unsigned int* sA = (unsigned int*)alloc((size_t)N * 64 * 4);
    unsigned int* wb = (unsigned int*)alloc((size_t)N * 64 * 4);  // reused as hb
    unsigned int* sb = (unsigned int*)alloc((size_t)N * 64 * 4);
    unsigned short* xb  = (unsigned short*)alloc((size_t)N * KP * 2);
    unsigned short* wbt = (unsigned short*)alloc((size_t)NCOLS * KP * 2);
    float* dis  = (float*)alloc((size_t)N * 4);
    int* cnt    = (int*)alloc((size_t)N * 4);
    int* off    = (int*)alloc((size_t)(N + 1) * 4);
    int* bsum   = (int*)alloc((size_t)256 * 4);
    int* bcur   = (int*)alloc((size_t)NBK * CPAD * 4);
    unsigned int* bkt = (unsigned int*)alloc((size_t)NBK * BCAP * 4);
    int* scol   = (int*)alloc((size_t)E * 4);
    float* Wc2  = (float*)alloc((size_t)128 * 8 * 4);
    float* s2   = (float*)alloc((size_t)N * 2 * 4);
    float* w2   = (float*)alloc((size_t)N * 2 * 4);

    hipMemsetAsync(cnt, 0, (size_t)N * 4, stream);
    hipMemsetAsync(bcur, 0, (size_t)NBK * CPAD * 4, stream);

    int gE = (E + 255) / 256;
    int gN = (N + 255) / 256;
    int NB = (N + 1023) / 1024;

    // conversions
    k_xb<<<(N * (KP / 8) + 255) / 256, 256, 0, stream>>>(x, xb, N);
    k_wbt<<<(NCOLS * (KP / 8) + 255) / 256, 256, 0, stream>>>(W1, wbt);
    k_wc2<<<4, 256, 0, stream>>>(W2, Wc2);

    // CSR build (bucketed, line-padded cursors)
    k_count<<<gE, 256, 0, stream>>>(erow, cnt, E);
    k_dis<<<gN, 256, 0, stream>>>(cnt, dis, N);
    k_scan1<<<NB, 256, 0, stream>>>(cnt, off, bsum, N);
    k_scan2<<<1, 256, 0, stream>>>(bsum, NB);
    k_scan3<<<gN, 256, 0, stream>>>(off, bsum, N, E);
    k_bucket<<<gE, 256, 0, stream>>>(erow, ecol, bcur, bkt, E);
    k_emit<<<NBK, 256, 0, stream>>>(bcur, bkt, off, scol, N);

    // layer 1: MFMA GEMM (g fast-varying for xb L2 reuse)
    dim3 g1(3, (N + 127) / 128);
    k_gemm1_mfma<<<g1, 256, 0, stream>>>(xb, wbt, dis, ub, sA, wb, N);

    int nw4 = (N + 3) / 4;
    int gP4 = (nw4 * 64 + 255) / 256;
    // sb = bf16( sA - 2*dis^2 * prop-sum(wb) )
    k_prop_b2b<<<gP4, 256, 0, stream>>>(off, scol, wb, sA, dis, sb, N);
    // hb(=wb) = bf16 relu( ub - dis * prop-sum(sb) + b1 )
    k_prop_b2f_relu<<<gP4, 256, 0, stream>>>(off, scol, sb, ub, dis, b1, wb, N);

    // layer 2
    k_gemm2<<<(N + 31) / 32, 256, 0, stream>>>(wb, Wc2, b2, dis, out, s2, w2, N);
    k_prop2_csr<<<gN, 256, 0, stream>>>(off, scol, w2, s2, dis, s2, 1, N);
    k_prop2_csr<<<gN, 256, 0, stream>>>(off, scol, s2, out, dis, out, 0, N);
}

// Round 11
// 697.927 us; speedup vs baseline: 2.0550x; 1.3375x over previous
//
#include <hip/hip_runtime.h>
#include <hip/hip_bf16.h>
#include <stdint.h>

#define NF 165
#define NH 128
#define KP 192          // padded K for MFMA
#define NCOLS 384
#define BSH 8           // rows per bucket = 256
#define BROWS 256
#define BCAP 6144       // whole-bucket capacity for emit LDS buffer
#define NSUB 8          // sub-buckets per bucket (one per XCD)
#define BSUBCAP 768     // per-(bucket,xcd) capacity (mean 512, sigma 22.6 -> +11 sigma)
#define CPAD 16         // cursor padding: 16 ints = 64B line

typedef __attribute__((ext_vector_type(8))) short bf16x8;
typedef __attribute__((ext_vector_type(4))) float f32x4;

// ---- bf16 helpers --------------------------------------------------------

__device__ __forceinline__ unsigned short f2bf(float f) {
    unsigned int u = __builtin_bit_cast(unsigned int, f);
    u = (u + 0x7FFFu + ((u >> 16) & 1u)) >> 16;   // RNE
    return (unsigned short)u;
}
__device__ __forceinline__ float bf2f_lo(unsigned int v) {
    return __builtin_bit_cast(float, v << 16);
}
__device__ __forceinline__ float bf2f_hi(unsigned int v) {
    return __builtin_bit_cast(float, v & 0xFFFF0000u);
}

// ---- CSR build ----------------------------------------------------------

// Level-1: append edges to XCD-local sub-buckets. blockIdx&7 tracks the XCD
// (dispatch round-robins WGs across XCDs) so cursor lines and payload stream
// heads stay resident in ONE XCD's L2 -> full-line writebacks, local atomics.
__global__ __launch_bounds__(256) void k_bucket(
        const int* __restrict__ erow, const int* __restrict__ ecol,
        int* __restrict__ bcur, unsigned int* __restrict__ bkt, int E) {
    int e = blockIdx.x * 256 + threadIdx.x;
    if (e >= E) return;
    int x = blockIdx.x & (NSUB - 1);
    int r = erow[e];
    int c = ecol[e];
    int sub = (r >> BSH) * NSUB + x;
    int pos = atomicAdd(&bcur[sub * CPAD], 1);
    if (pos < BSUBCAP)
        bkt[(size_t)sub * BSUBCAP + pos] =
            ((unsigned)(r & (BROWS - 1)) << 18) | (unsigned)c;
}

// Histogram bucket records -> cnt (replaces 3.2M random global atomics with
// LDS atomics + sequential writes).
__global__ __launch_bounds__(256) void k_hist(
        const int* __restrict__ bcur, const unsigned int* __restrict__ bkt,
        int* __restrict__ cnt, int N) {
    __shared__ int h[BROWS];
    int b = blockIdx.x;
    int t = threadIdx.x;
    h[t] = 0;
    __syncthreads();
#pragma unroll
    for (int x = 0; x < NSUB; ++x) {
        int sub = b * NSUB + x;
        int nb = bcur[sub * CPAD];
        if (nb > BSUBCAP) nb = BSUBCAP;
        const unsigned int* src = bkt + (size_t)sub * BSUBCAP;
        for (int i = t; i < nb; i += 256)
            atomicAdd(&h[src[i] >> 18], 1);
    }
    __syncthreads();
    int base = b << BSH;
    if (base + t < N) cnt[base + t] = h[t];
}

__global__ __launch_bounds__(256) void k_dis(
        const int* __restrict__ cnt, float* __restrict__ dis, int N) {
    int i = blockIdx.x * 256 + threadIdx.x;
    if (i >= N) return;
    int d = cnt[i];
    dis[i] = (d > 0) ? rsqrtf((float)d) : 0.0f;
}

__global__ __launch_bounds__(256) void k_scan1(
        const int* __restrict__ cnt, int* __restrict__ off,
        int* __restrict__ bsum, int N) {
    __shared__ int sh[256];
    int t = threadIdx.x;
    int base = blockIdx.x * 1024 + t * 4;
    int v0 = (base + 0 < N) ? cnt[base + 0] : 0;
    int v1 = (base + 1 < N) ? cnt[base + 1] : 0;
    int v2 = (base + 2 < N) ? cnt[base + 2] : 0;
    int v3 = (base + 3 < N) ? cnt[base + 3] : 0;
    int tsum = v0 + v1 + v2 + v3;
    sh[t] = tsum;
    __syncthreads();
#pragma unroll
    for (int ofs = 1; ofs < 256; ofs <<= 1) {
        int x = (t >= ofs) ? sh[t - ofs] : 0;
        __syncthreads();
        sh[t] += x;
        __syncthreads();
    }
    int excl = sh[t] - tsum;
    if (t == 255) bsum[blockIdx.x] = sh[t];
    if (base + 0 < N) off[base + 0] = excl;
    excl += v0;
    if (base + 1 < N) off[base + 1] = excl;
    excl += v1;
    if (base + 2 < N) off[base + 2] = excl;
    excl += v2;
    if (base + 3 < N) off[base + 3] = excl;
}

__global__ __launch_bounds__(256) void k_scan2(int* __restrict__ bsum, int NB) {
    __shared__ int sh[256];
    int t = threadIdx.x;
    int v = (t < NB) ? bsum[t] : 0;
    sh[t] = v;
    __syncthreads();
#pragma unroll
    for (int ofs = 1; ofs < 256; ofs <<= 1) {
        int x = (t >= ofs) ? sh[t - ofs] : 0;
        __syncthreads();
        sh[t] += x;
        __syncthreads();
    }
    if (t < NB) bsum[t] = sh[t] - v;
}

__global__ __launch_bounds__(256) void k_scan3(
        int* __restrict__ off, const int* __restrict__ bsum, int N, int E) {
    int i = blockIdx.x * 256 + threadIdx.x;
    if (i >= N) return;
    off[i] = off[i] + bsum[i >> 10];
    if (i == 0) off[N] = E;
}

// Level-2: one block per bucket; place edges at exact CSR slots via LDS,
// then stream out coalesced.
__global__ __launch_bounds__(256) void k_emit(
        const int* __restrict__ bcur, const unsigned int* __restrict__ bkt,
        const int* __restrict__ off, int* __restrict__ scol, int N) {
    __shared__ unsigned colbuf[BCAP];
    __shared__ int rowoff[BROWS + 1];
    __shared__ int cursor[BROWS];

    int b = blockIdx.x;
    int base = b << BSH;
    int nrows = N - base;
    if (nrows > BROWS) nrows = BROWS;
    int t = threadIdx.x;

    for (int i = t; i <= nrows; i += 256) rowoff[i] = off[base + i];
    if (t < BROWS) cursor[t] = 0;
    __syncthreads();

    int regionStart = rowoff[0];
    int total = rowoff[nrows] - regionStart;

#pragma unroll
    for (int x = 0; x < NSUB; ++x) {
        int sub = b * NSUB + x;
        int nb = bcur[sub * CPAD];
        if (nb > BSUBCAP) nb = BSUBCAP;
        const unsigned int* src = bkt + (size_t)sub * BSUBCAP;
        for (int i = t; i < nb; i += 256) {
            unsigned v = src[i];
            int rl = v >> 18;
            unsigned c = v & 0x3FFFFu;
            int pos = (rowoff[rl] - regionStart) + atomicAdd(&cursor[rl], 1);
            if (pos < BCAP) colbuf[pos] = c;
        }
    }
    __syncthreads();

    for (int i = t; i < total; i += 256) scol[regionStart + i] = (int)colbuf[i];
}

// ---- conversions ---------------------------------------------------------

__global__ __launch_bounds__(256) void k_xb(
        const float* __restrict__ x, unsigned short* __restrict__ xb, int N) {
    int gid = blockIdx.x * 256 + threadIdx.x;
    if (gid >= N * (KP / 8)) return;
    int row = gid / (KP / 8);
    int k0 = (gid % (KP / 8)) * 8;
    unsigned short v[8];
#pragma unroll
    for (int i = 0; i < 8; ++i) {
        int k = k0 + i;
        v[i] = (k < NF) ? f2bf(x[(size_t)row * NF + k]) : (unsigned short)0;
    }
    uint4 pk;
    pk.x = (unsigned)v[0] | ((unsigned)v[1] << 16);
    pk.y = (unsigned)v[2] | ((unsigned)v[3] << 16);
    pk.z = (unsigned)v[4] | ((unsigned)v[5] << 16);
    pk.w = (unsigned)v[6] | ((unsigned)v[7] << 16);
    *(uint4*)(xb + (size_t)row * KP + k0) = pk;
}

__global__ __launch_bounds__(256) void k_wbt(
        const float* __restrict__ W1, unsigned short* __restrict__ wbt) {
    int gid = blockIdx.x * 256 + threadIdx.x;
    if (gid >= NCOLS * (KP / 8)) return;
    int col = gid / (KP / 8);
    int k0 = (gid % (KP / 8)) * 8;
    int cc = col & 127;
    unsigned short v[8];
#pragma unroll
    for (int i = 0; i < 8; ++i) {
        int k = k0 + i;
        float f = 0.0f;
        if (k < NF) {
            if (col < 128)      f = W1[k * 128 + cc] - W1[42240 + k * 128 + cc];
            else if (col < 256) f = W1[21120 + k * 128 + cc];
            else                f = W1[42240 + k * 128 + cc];
        }
        v[i] = f2bf(f);
    }
    uint4 pk;
    pk.x = (unsigned)v[0] | ((unsigned)v[1] << 16);
    pk.y = (unsigned)v[2] | ((unsigned)v[3] << 16);
    pk.z = (unsigned)v[4] | ((unsigned)v[5] << 16);
    pk.w = (unsigned)v[6] | ((unsigned)v[7] << 16);
    *(uint4*)(wbt + (size_t)col * KP + k0) = pk;
}

// Wc2[128][8] with k in interleaved-hidden layout: k_lin 2c->(c), 2c+1->(c+64)
__global__ __launch_bounds__(256) void k_wc2(const float* __restrict__ W2,
                                             float* __restrict__ Wc2) {
    int gid = blockIdx.x * 256 + threadIdx.x;
    if (gid >= 128 * 8) return;
    int k = gid >> 3;
    int c = gid & 7;
    int ko = (k & 1) ? (k >> 1) + 64 : (k >> 1);
    float v = 0.0f;
    if (c < 2)      v = W2[ko * 2 + c] - W2[512 + ko * 2 + c];
    else if (c < 4) v = W2[256 + ko * 2 + (c - 2)];
    else if (c < 6) v = W2[512 + ko * 2 + (c - 4)];
    Wc2[gid] = v;
}

// ---- GEMM1 via MFMA ------------------------------------------------------
// g==0 -> ub = u (bf16); g==1 -> sA = dis*s (bf16); g==2 -> wb = dis*w (bf16)
__global__ __launch_bounds__(256) void k_gemm1_mfma(
        const unsigned short* __restrict__ xb, const unsigned short* __restrict__ wbt,
        const float* __restrict__ dis,
        unsigned int* __restrict__ ub, unsigned int* __restrict__ sA,
        unsigned int* __restrict__ wb, int N) {
    __shared__ unsigned short As[128][40];
    __shared__ unsigned short Bs[128][40];

    int tid = threadIdx.x;
    int w = tid >> 6;
    int lane = tid & 63;
    int l15 = lane & 15;
    int l16 = lane >> 4;
    int g = blockIdx.x;
    int brow = blockIdx.y * 128;
    int gcol = g * 128;

    int sr = tid >> 1;
    int sk = (tid & 1) * 16;

    f32x4 acc[2][8] = {};

    for (int kc = 0; kc < 6; ++kc) {
        int k0 = kc * 32;
        uint4 va0 = {0, 0, 0, 0}, va1 = {0, 0, 0, 0};
        if (brow + sr < N) {
            const unsigned short* asrc = xb + (size_t)(brow + sr) * KP + k0 + sk;
            va0 = *(const uint4*)asrc;
            va1 = *(const uint4*)(asrc + 8);
        }
        const unsigned short* bsrc = wbt + (size_t)(gcol + sr) * KP + k0 + sk;
        uint4 vb0 = *(const uint4*)bsrc;
        uint4 vb1 = *(const uint4*)(bsrc + 8);
        __syncthreads();
        *(uint4*)&As[sr][sk] = va0;
        *(uint4*)&As[sr][sk + 8] = va1;
        *(uint4*)&Bs[sr][sk] = vb0;
        *(uint4*)&Bs[sr][sk + 8] = vb1;
        __syncthreads();

        bf16x8 a[2], b[8];
#pragma unroll
        for (int m = 0; m < 2; ++m)
            a[m] = *(const bf16x8*)&As[w * 32 + m * 16 + l15][l16 * 8];
#pragma unroll
        for (int n = 0; n < 8; ++n)
            b[n] = *(const bf16x8*)&Bs[n * 16 + l15][l16 * 8];
#pragma unroll
        for (int m = 0; m < 2; ++m)
#pragma unroll
            for (int n = 0; n < 8; ++n)
                acc[m][n] = __builtin_amdgcn_mfma_f32_16x16x32_bf16(
                    a[m], b[n], acc[m][n], 0, 0, 0);
    }

    unsigned int* dst = (g == 0) ? ub : (g == 1) ? sA : wb;
#pragma unroll
    for (int m = 0; m < 2; ++m) {
#pragma unroll
        for (int reg = 0; reg < 4; ++reg) {
            int row = brow + w * 32 + m * 16 + l16 * 4 + reg;
            if (row >= N) continue;
            float sc = (g == 0) ? 1.0f : dis[row];
#pragma unroll
            for (int n = 0; n < 4; ++n) {
                int c = n * 16 + l15;
                float lo = sc * acc[m][n][reg];
                float hi = sc * acc[m][n + 4][reg];
                dst[(size_t)row * 64 + c] =
                    (unsigned)f2bf(lo) | ((unsigned)f2bf(hi) << 16);
            }
        }
    }
}

// ---- 128-wide props: 4 rows/wave, 16 lanes/row, uint4 gathers, unroll-2 ---

// sb[r] = bf16( sA[r] - 2*dis[r]^2 * sum_e wb[col] )
__global__ __launch_bounds__(256) void k_prop_b2b(
        const int* __restrict__ off, const int* __restrict__ scol,
        const unsigned int* __restrict__ srcb, const unsigned int* __restrict__ addb,
        const float* __restrict__ dis, unsigned int* __restrict__ dstb, int N) {
    int wid = (blockIdx.x * 256 + threadIdx.x) >> 6;
    int lane = threadIdx.x & 63;
    int g = lane >> 4, q = lane & 15;
    int r = wid * 4 + g;
    if (r >= N) return;
    int e = off[r], end = off[r + 1];
    const uint4* src4 = (const uint4*)srcb;
    float a[8] = {}, b[8] = {};
    for (; e + 2 <= end; e += 2) {
        int c0 = scol[e], c1 = scol[e + 1];
        uint4 v0 = src4[(size_t)c0 * 16 + q];
        uint4 v1 = src4[(size_t)c1 * 16 + q];
        unsigned vv0[4] = {v0.x, v0.y, v0.z, v0.w};
        unsigned vv1[4] = {v1.x, v1.y, v1.z, v1.w};
#pragma unroll
        for (int j = 0; j < 4; ++j) {
            a[2 * j] += bf2f_lo(vv0[j]); a[2 * j + 1] += bf2f_hi(vv0[j]);
            b[2 * j] += bf2f_lo(vv1[j]); b[2 * j + 1] += bf2f_hi(vv1[j]);
        }
    }
    if (e < end) {
        int c0 = scol[e];
        uint4 v0 = src4[(size_t)c0 * 16 + q];
        unsigned vv0[4] = {v0.x, v0.y, v0.z, v0.w};
#pragma unroll
        for (int j = 0; j < 4; ++j) {
            a[2 * j] += bf2f_lo(vv0[j]); a[2 * j + 1] += bf2f_hi(vv0[j]);
        }
    }
    float d = dis[r];
    float m2 = -2.0f * d * d;
    uint4 ad = ((const uint4*)addb)[(size_t)r * 16 + q];
    unsigned adp[4] = {ad.x, ad.y, ad.z, ad.w};
    uint4 o;
    unsigned* op = (unsigned*)&o;
#pragma unroll
    for (int j = 0; j < 4; ++j) {
        float lo = bf2f_lo(adp[j]) + m2 * (a[2 * j] + b[2 * j]);
        float hi = bf2f_hi(adp[j]) + m2 * (a[2 * j + 1] + b[2 * j + 1]);
        op[j] = (unsigned)f2bf(lo) | ((unsigned)f2bf(hi) << 16);
    }
    ((uint4*)dstb)[(size_t)r * 16 + q] = o;
}

// hb[r] = bf16( relu( ub[r] - dis[r] * sum_e sb[col] + b1 ) )
__global__ __launch_bounds__(256) void k_prop_b2f_relu(
        const int* __restrict__ off, const int* __restrict__ scol,
        const unsigned int* __restrict__ srcb, const unsigned int* __restrict__ addb,
        const float* __restrict__ dis, const float* __restrict__ b1,
        unsigned int* __restrict__ hb, int N) {
    int wid = (blockIdx.x * 256 + threadIdx.x) >> 6;
    int lane = threadIdx.x & 63;
    int g = lane >> 4, q = lane & 15;
    int r = wid * 4 + g;
    if (r >= N) return;
    int e = off[r], end = off[r + 1];
    const uint4* src4 = (const uint4*)srcb;
    float a[8] = {}, b[8] = {};
    for (; e + 2 <= end; e += 2) {
        int c0 = scol[e], c1 = scol[e + 1];
        uint4 v0 = src4[(size_t)c0 * 16 + q];
        uint4 v1 = src4[(size_t)c1 * 16 + q];
        unsigned vv0[4] = {v0.x, v0.y, v0.z, v0.w};
        unsigned vv1[4] = {v1.x, v1.y, v1.z, v1.w};
#pragma unroll
        for (int j = 0; j < 4; ++j) {
            a[2 * j] += bf2f_lo(vv0[j]); a[2 * j + 1] += bf2f_hi(vv0[j]);
            b[2 * j] += bf2f_lo(vv1[j]); b[2 * j + 1] += bf2f_hi(vv1[j]);
        }
    }
    if (e < end) {
        int c0 = scol[e];
        uint4 v0 = src4[(size_t)c0 * 16 + q];
        unsigned vv0[4] = {v0.x, v0.y, v0.z, v0.w};
#pragma unroll
        for (int j = 0; j < 4; ++j) {
            a[2 * j] += bf2f_lo(vv0[j]); a[2 * j + 1] += bf2f_hi(vv0[j]);
        }
    }
    float m1 = -dis[r];
    uint4 ad = ((const uint4*)addb)[(size_t)r * 16 + q];
    unsigned adp[4] = {ad.x, ad.y, ad.z, ad.w};
    uint4 o;
    unsigned* op = (unsigned*)&o;
#pragma unroll
    for (int j = 0; j < 4; ++j) {
        int c = q * 4 + j;
        float lo = fmaxf(bf2f_lo(adp[j]) + m1 * (a[2 * j] + b[2 * j]) + b1[c], 0.0f);
        float hi = fmaxf(bf2f_hi(adp[j]) + m1 * (a[2 * j + 1] + b[2 * j + 1]) + b1[c + 64], 0.0f);
        op[j] = (unsigned)f2bf(lo) | ((unsigned)f2bf(hi) << 16);
    }
    ((uint4*)hb)[(size_t)r * 16 + q] = o;
}

// GEMM2: hb[N,64] (bf16 pairs) @ Wc2[128,8] -> out(+b2) f32, s2=dis*s2raw, w2=dis*w2raw
__global__ __launch_bounds__(256) void k_gemm2(
        const unsigned int* __restrict__ hb, const float* __restrict__ Wc2,
        const float* __restrict__ b2, const float* __restrict__ dis,
        float* __restrict__ out, float* __restrict__ s2, float* __restrict__ w2,
        int N) {
    __shared__ float Ws[128 * 8];
    int tid = threadIdx.x;
    for (int idx = tid; idx < 128 * 8; idx += 256) Ws[idx] = Wc2[idx];
    __syncthreads();

    int rl = tid >> 3;
    int sub = tid & 7;
    int row = blockIdx.x * 32 + rl;
    if (row >= N) return;

    float4 accA = {0, 0, 0, 0};
    float4 accB = {0, 0, 0, 0};
    const uint4* hp = (const uint4*)(hb + (size_t)row * 64 + sub * 8);
#pragma unroll
    for (int qq = 0; qq < 2; ++qq) {
        uint4 hv = hp[qq];
        unsigned hu[4] = {hv.x, hv.y, hv.z, hv.w};
#pragma unroll
        for (int t = 0; t < 4; ++t) {
            int kl = sub * 16 + qq * 8 + 2 * t;
            float he0 = bf2f_lo(hu[t]);
            float he1 = bf2f_hi(hu[t]);
            const float* w0 = &Ws[kl * 8];
            const float* w1 = &Ws[(kl + 1) * 8];
            accA.x += he0 * w0[0] + he1 * w1[0];
            accA.y += he0 * w0[1] + he1 * w1[1];
            accA.z += he0 * w0[2] + he1 * w1[2];
            accA.w += he0 * w0[3] + he1 * w1[3];
            accB.x += he0 * w0[4] + he1 * w1[4];
            accB.y += he0 * w0[5] + he1 * w1[5];
        }
    }
#pragma unroll
    for (int off = 4; off; off >>= 1) {
        accA.x += __shfl_xor(accA.x, off);
        accA.y += __shfl_xor(accA.y, off);
        accA.z += __shfl_xor(accA.z, off);
        accA.w += __shfl_xor(accA.w, off);
        accB.x += __shfl_xor(accB.x, off);
        accB.y += __shfl_xor(accB.y, off);
    }
    if (sub == 0) {
        float d = dis[row];
        out[(size_t)row * 2 + 0] = accA.x + b2[0];
        out[(size_t)row * 2 + 1] = accA.y + b2[1];
        s2[(size_t)row * 2 + 0] = d * accA.z;
        s2[(size_t)row * 2 + 1] = d * accA.w;
        w2[(size_t)row * 2 + 0] = d * accB.x;
        w2[(size_t)row * 2 + 1] = d * accB.y;
    }
}

// CSR prop, 2-wide: dst[r] = add[r] + m * sum src[col], m = sq ? -2*dis^2 : -dis.
__global__ __launch_bounds__(256) void k_prop2_csr(
        const int* __restrict__ off, const int* __restrict__ scol,
        const float* __restrict__ src, const float* __restrict__ add,
        const float* __restrict__ dis, float* __restrict__ dst,
        int sq, int N) {
    int r = blockIdx.x * 256 + threadIdx.x;
    if (r >= N) return;
    int e0 = off[r], e1 = off[r + 1];
    float a0 = 0.0f, a1 = 0.0f;
    for (int e = e0; e < e1; ++e) {
        int c = scol[e];
        float2 v = *(const float2*)(src + (size_t)c * 2);
        a0 += v.x;
        a1 += v.y;
    }
    float d = dis[r];
    float m = sq ? (-2.0f * d * d) : (-d);
    float2 ad = *(const float2*)(add + (size_t)r * 2);
    float2 o = {ad.x + m * a0, ad.y + m * a1};
    *(float2*)(dst + (size_t)r * 2) = o;
}

extern "C" void kernel_launch(void* const* d_in, const int* in_sizes, int n_in,
                              void* d_out, int out_size, void* d_ws, size_t ws_size,
                              hipStream_t stream) {
    const float* x   = (const float*)d_in[0];
    const int* eidx  = (const int*)d_in[1];
    const float* W1  = (const float*)d_in[2];
    const float* b1  = (const float*)d_in[3];
    const float* W2  = (const float*)d_in[4];
    const float* b2  = (const float*)d_in[5];
    float* out       = (float*)d_out;

    int N = in_sizes[0] / NF;
    int E = in_sizes[1] / 2;
    const int* erow = eidx;
    const int* ecol = eidx + E;
    int NBK = (N + BROWS - 1) >> BSH;

    char* p = (char*)d_ws;
    auto alloc = [&](size_t bytes) {
        char* q = p;
        p += (bytes + 255) & ~(size_t)255;
        return q;
    };
    unsigned int* ub = (unsigned int*)alloc((size_t)N * 64 * 4);
    unsigned int* sA = (unsigned int*)alloc((size_t)N * 64 * 4);
    unsigned int* wb = (unsigned int*)alloc((size_t)N * 64 * 4);  // reused as hb
    unsigned int* sb = (unsigned int*)alloc((size_t)N * 64 * 4);
    unsigned short* xb  = (unsigned short*)alloc((size_t)N * KP * 2);
    unsigned short* wbt = (unsigned short*)alloc((size_t)NCOLS * KP * 2);
    float* dis  = (float*)alloc((size_t)N * 4);
    int* cnt    = (int*)alloc((size_t)N * 4);
    int* off    = (int*)alloc((size_t)(N + 1) * 4);
    int* bsum   = (int*)alloc((size_t)256 * 4);
    int* bcur   = (int*)alloc((size_t)NBK * NSUB * CPAD * 4);
    unsigned int* bkt = (unsigned int*)alloc((size_t)NBK * NSUB * BSUBCAP * 4);
    int* scol   = (int*)alloc((size_t)E * 4);
    float* Wc2  = (float*)alloc((size_t)128 * 8 * 4);
    float* s2   = (float*)alloc((size_t)N * 2 * 4);
    float* w2   = (float*)alloc((size_t)N * 2 * 4);

    hipMemsetAsync(bcur, 0, (size_t)NBK * NSUB * CPAD * 4, stream);

    int gE = (E + 255) / 256;
    int gN = (N + 255) / 256;
    int NB = (N + 1023) / 1024;

    // conversions
    k_xb<<<(N * (KP / 8) + 255) / 256, 256, 0, stream>>>(x, xb, N);
    k_wbt<<<(NCOLS * (KP / 8) + 255) / 256, 256, 0, stream>>>(W1, wbt);
    k_wc2<<<4, 256, 0, stream>>>(W2, Wc2);

    // CSR build (XCD-local sub-buckets)
    k_bucket<<<gE, 256, 0, stream>>>(erow, ecol, bcur, bkt, E);
    k_hist<<<NBK, 256, 0, stream>>>(bcur, bkt, cnt, N);
    k_dis<<<gN, 256, 0, stream>>>(cnt, dis, N);
    k_scan1<<<NB, 256, 0, stream>>>(cnt, off, bsum, N);
    k_scan2<<<1, 256, 0, stream>>>(bsum, NB);
    k_scan3<<<gN, 256, 0, stream>>>(off, bsum, N, E);
    k_emit<<<NBK, 256, 0, stream>>>(bcur, bkt, off, scol, N);

    // layer 1: MFMA GEMM (g fast-varying for xb L2 reuse)
    dim3 g1(3, (N + 127) / 128);
    k_gemm1_mfma<<<g1, 256, 0, stream>>>(xb, wbt, dis, ub, sA, wb, N);

    int nw4 = (N + 3) / 4;
    int gP4 = (nw4 * 64 + 255) / 256;
    // sb = bf16( sA - 2*dis^2 * prop-sum(wb) )
    k_prop_b2b<<<gP4, 256, 0, stream>>>(off, scol, wb, sA, dis, sb, N);
    // hb(=wb) = bf16 relu( ub - dis * prop-sum(sb) + b1 )
    k_prop_b2f_relu<<<gP4, 256, 0, stream>>>(off, scol, sb, ub, dis, b1, wb, N);

    // layer 2
    k_gemm2<<<(N + 31) / 32, 256, 0, stream>>>(wb, Wc2, b2, dis, out, s2, w2, N);
    k_prop2_csr<<<gN, 256, 0, stream>>>(off, scol, w2, s2, dis, s2, 1, N);
    k_prop2_csr<<<gN, 256, 0, stream>>>(off, scol, s2, out, dis, out, 0, N);
}